// Round 6
// baseline (157.755 us; speedup 1.0000x reference)
//
#include <hip/hip_runtime.h>

namespace {
constexpr int N_ = 16, C_ = 112, H_ = 48, W_ = 48, HW_ = 2304;
// ws float offsets
constexpr int WS_T7 = 0;         // N*H = 768
constexpr int WS_T17 = 768;      // N*7 = 112
constexpr int WS_A = 1024;       // N*C = 1792
constexpr int WS_V = 4096;       // N*C*7 = 12544
constexpr int WS_G = 16896;      // N*C*C = 200704
constexpr int WS_SPART = 217600; // nch*N*C*C
}

__device__ __forceinline__ float f4e(const float4& v, int e) {
  return e == 0 ? v.x : e == 1 ? v.y : e == 2 ? v.z : v.w;
}

// ---------------------------------------------------------------------------
// K1: channel-mean rows -> t7. t7 value from mean-row h' lands at (h'+2)%48.
// grid (16, N), 192 threads, 3 h-rows per block
__global__ __launch_bounds__(192) void ath_stats(const float* __restrict__ x,
                                                 const float* __restrict__ p7,
                                                 float* __restrict__ ws) {
  const int hg = blockIdx.x;
  const int n = blockIdx.y;
  const int tid = threadIdx.x;
  __shared__ float mxs[144];
  if (tid < 144) {
    const float* xb = x + (size_t)n * C_ * HW_ + hg * 144 + tid;
    float a0 = 0.f, a1 = 0.f, a2 = 0.f, a3 = 0.f;
    for (int c = 0; c < C_; c += 4) {
      a0 += xb[(size_t)c * HW_];
      a1 += xb[(size_t)(c + 1) * HW_];
      a2 += xb[(size_t)(c + 2) * HW_];
      a3 += xb[(size_t)(c + 3) * HW_];
    }
    mxs[tid] = (a0 + a1 + a2 + a3) * (1.0f / 112.0f);
  }
  __syncthreads();
  if (tid < 3) {
    float s = 0.f;
    for (int k = 0; k < 3; ++k)
      for (int wp = 0; wp < W_; ++wp) {
        int j = 3 * k + wp - 3;
        if (j >= 0 && j < W_) s += mxs[tid * 48 + j] * p7[k * W_ + wp];
      }
    const int hsrc = hg * 3 + tid;
    ws[WS_T7 + n * H_ + (hsrc + 2) % 48] = s;  // S3=+1,S6=+1 -> +2 shift
  }
}

// ---------------------------------------------------------------------------
// K3 (now also computes t17 locally; block c==0 publishes it for assemble):
// per (n,c): V[n,c,m] (mod-7 bucket sums), A'[n,c]. grid (C,N), 64 thr
__global__ __launch_bounds__(64) void ath_colstats(const float* __restrict__ x,
                                                   const float* __restrict__ p19,
                                                   float* __restrict__ ws) {
  const int c = blockIdx.x, n = blockIdx.y;
  const int tid = threadIdx.x;
  __shared__ float t7s[48];
  if (tid < 48) t7s[tid] = ws[WS_T7 + n * H_ + tid];
  const float* xb = x + ((size_t)n * C_ + c) * HW_;
  float rowsum = 0.f;
  if (tid < 48) {
    const float4* xr = (const float4*)(xb + tid * W_);
#pragma unroll
    for (int q = 0; q < 12; ++q) {
      float4 v = xr[q];
      rowsum += v.x + v.y + v.z + v.w;
    }
  }
  float vb[7] = {0.f, 0.f, 0.f, 0.f, 0.f, 0.f, 0.f};
#pragma unroll
  for (int jj = 0; jj < 9; ++jj) {
    int p0 = (tid + 64 * jj) * 4;
    float4 v = *(const float4*)&xb[p0];
    int h = p0 / 48;
    int w = p0 - h * 48;
    int m0 = (w - h + 49) % 7;
#pragma unroll
    for (int r = 0; r < 4; ++r) {
      int mr = m0 + r;
      mr = (mr >= 7) ? mr - 7 : mr;
      float val = f4e(v, r);
#pragma unroll
      for (int j = 0; j < 7; ++j) vb[j] += (mr == j) ? val : 0.f;
    }
  }
#pragma unroll
  for (int j = 0; j < 7; ++j) {
#pragma unroll
    for (int off = 32; off >= 1; off >>= 1) vb[j] += __shfl_xor(vb[j], off);
  }
  if (tid == 0) {
#pragma unroll
    for (int j = 0; j < 7; ++j) ws[WS_V + ((size_t)n * C_ + c) * 7 + j] = vb[j];
  }
  // local t17[kk] = (1/48) sum_h |t7pad[2kk+h-6]|
  float t17l[7];
  float T = 0.f;
#pragma unroll
  for (int kk = 0; kk < 7; ++kk) {
    float s = 0.f;
    for (int hh = 0; hh < 48; ++hh) {
      int j = 2 * kk + hh - 6;
      if (j >= 0 && j < 48) s += fabsf(t7s[j]);
    }
    t17l[kk] = s * (1.0f / 48.0f);
    T += t17l[kk];
  }
  if (c == 0 && tid < 7) ws[WS_T17 + n * 7 + tid] = t17l[tid];
  // A'[n,c] = (2/48)*p19[c]*sum_h t7[h]*(rowsum[h] + D[(c-h)%7]), D[s]=7T - t17[(s+6)%7]
  float term = 0.f;
  if (tid < 48) {
    int idx6 = ((c - tid + 6) % 7 + 7) % 7;
    float D = 7.f * T - t17l[idx6];
    term = t7s[tid] * 0.f + t7s[tid] * (rowsum + D);  // t7s == t7
  }
#pragma unroll
  for (int off = 32; off >= 1; off >>= 1) term += __shfl_xor(term, off);
  if (tid == 0) ws[WS_A + n * C_ + c] = p19[c] * term * (2.0f / 48.0f);
}

// ---------------------------------------------------------------------------
// K4: Gram partials. grid N*nch, 256 threads, 8x8 tile on c-padded-128 slab,
// 48-row LDS passes.
__global__ __launch_bounds__(256) void ath_gram(const float* __restrict__ x,
                                                float* __restrict__ ws,
                                                int nch, int KC) {
  const int bid = blockIdx.x;
  const int n = bid / nch;
  const int kc = bid - n * nch;
  const int p0 = kc * KC;
  const int tid = threadIdx.x;
  __shared__ float xs[48][132];
  for (int idx = tid; idx < 48 * 16; idx += 256) {
    int k = idx / 16, cc = 112 + (idx % 16);
    xs[k][cc] = 0.f;
  }
  float acc[8][8];
#pragma unroll
  for (int a = 0; a < 8; ++a)
#pragma unroll
    for (int b = 0; b < 8; ++b) acc[a][b] = 0.f;
  const int tc = tid >> 4, ti = tid & 15;
  const int c0 = tc * 8, i0 = ti * 8;
  const float* xb = x + (size_t)n * C_ * HW_;
  for (int ks = 0; ks < KC; ks += 48) {
    __syncthreads();
    for (int idx = tid; idx < C_ * 48; idx += 256) {
      int cc = idx / 48, k = idx - cc * 48;
      xs[k][cc] = xb[(size_t)cc * HW_ + p0 + ks + k];
    }
    __syncthreads();
#pragma unroll 2
    for (int k = 0; k < 48; ++k) {
      float4 a0 = *(const float4*)&xs[k][c0];
      float4 a1 = *(const float4*)&xs[k][c0 + 4];
      float4 b0 = *(const float4*)&xs[k][i0];
      float4 b1 = *(const float4*)&xs[k][i0 + 4];
      float av[8] = {a0.x, a0.y, a0.z, a0.w, a1.x, a1.y, a1.z, a1.w};
      float bv[8] = {b0.x, b0.y, b0.z, b0.w, b1.x, b1.y, b1.z, b1.w};
#pragma unroll
      for (int r = 0; r < 8; ++r)
#pragma unroll
        for (int q = 0; q < 8; ++q) acc[r][q] += av[r] * bv[q];
    }
  }
  if (c0 < 112 && i0 < 112) {
    float* sp = ws + WS_SPART + (size_t)bid * (C_ * C_);
#pragma unroll
    for (int r = 0; r < 8; ++r) {
      *(float4*)&sp[(c0 + r) * C_ + i0] =
          make_float4(acc[r][0], acc[r][1], acc[r][2], acc[r][3]);
      *(float4*)&sp[(c0 + r) * C_ + i0 + 4] =
          make_float4(acc[r][4], acc[r][5], acc[r][6], acc[r][7]);
    }
  }
}

// ---------------------------------------------------------------------------
// K5: G'[n,c,i] = p19[c]*(S + sum_m t17[(c+m)%7]*V[n,i,m]) / (48*sqrt(112))
__global__ __launch_bounds__(256) void ath_assemble(const float* __restrict__ p19,
                                                    float* __restrict__ ws,
                                                    int nch) {
  const int idx4 = blockIdx.x * 256 + threadIdx.x;
  if (idx4 >= N_ * C_ * C_ / 4) return;
  const int n = idx4 / 3136;
  const int r4 = idx4 - n * 3136;
  const int c = (r4 * 4) / C_;
  const int i0 = (r4 * 4) - c * C_;
  float4 s = make_float4(0.f, 0.f, 0.f, 0.f);
  for (int kc = 0; kc < nch; ++kc) {
    float4 v = *(const float4*)&ws[WS_SPART + (size_t)(n * nch + kc) * (C_ * C_) + r4 * 4];
    s.x += v.x; s.y += v.y; s.z += v.z; s.w += v.w;
  }
  const float* t17p = ws + WS_T17 + n * 7;
  const float scale = 1.0f / (48.0f * sqrtf(112.0f));
  const float pc = p19[c];
  float o[4];
#pragma unroll
  for (int e = 0; e < 4; ++e) {
    const float* vp = ws + WS_V + ((size_t)n * C_ + i0 + e) * 7;
    float t = 0.f;
    int j0 = c % 7;
#pragma unroll
    for (int m = 0; m < 7; ++m) {
      int jj = j0 + m;
      jj = (jj >= 7) ? jj - 7 : jj;
      t += t17p[jj] * vp[m];
    }
    o[e] = pc * (f4e(s, e) + t) * scale;
  }
  *(float4*)&ws[WS_G + idx4 * 4] = make_float4(o[0], o[1], o[2], o[3]);
}

// ---------------------------------------------------------------------------
// K6 fused conv + GEMM, 384 threads (6 waves, ALL active), split-K over input
// channels: worker = tid%192 owns (7 o-ch x 4 w), half = tid/192 owns 56 of
// the 112 contraction channels. LDS reduction (stride-29 pad) merges halves.
// 18 waves/CU (vs 9 working before) to hide LDS/L2 latency under VALU issue.
__device__ __forceinline__ void load_u(float4 (&u)[8], const float (*xs)[52],
                                       int ii, int w0) {
#pragma unroll
  for (int r = 0; r < 4; ++r) {
    u[2 * r] = *(const float4*)&xs[ii + r][w0];
    u[2 * r + 1] = *(const float4*)&xs[ii + r][w0 + 4];
  }
}
__device__ __forceinline__ void conv_fma(float (&accj)[4], const float4 (&u)[8],
                                         const float4 (&wv)[3]) {
#pragma unroll
  for (int r = 0; r < 4; ++r)
#pragma unroll
    for (int kx = 0; kx < 3; ++kx) {
      const int wi = 3 * r + kx;
      float w = f4e(wv[wi >> 2], wi & 3);
#pragma unroll
      for (int l = 0; l < 4; ++l) {
        const int t = l + 2 * kx;
        accj[l] += w * f4e(u[2 * r + (t >> 2)], t & 3);
      }
    }
}

__global__ __launch_bounds__(384, 5) void ath_fused(const float* __restrict__ x,
                                                    const float* __restrict__ cw,
                                                    const float* __restrict__ ws,
                                                    float* __restrict__ out) {
  const int h = blockIdx.x, n = blockIdx.y;
  const int tid = threadIdx.x;
  __shared__ float xs[C_][52];   // x at cols 2..49 (zeros 0,1,50,51); t13 -> cols 0..47
  __shared__ float red[192 * 29]; // split-K reduction buffer (stride 29: conflict-free)
  const float* xb = x + (size_t)n * C_ * HW_ + h * W_;
  for (int idx = tid; idx < C_ * 12; idx += 384) {
    int i = idx / 12, q = idx - i * 12;
    float4 v = *(const float4*)&xb[(size_t)i * HW_ + 4 * q];
    *(float2*)&xs[i][4 * q + 2] = float2{v.x, v.y};
    *(float2*)&xs[i][4 * q + 4] = float2{v.z, v.w};
  }
  for (int idx = tid; idx < C_ * 4; idx += 384) {
    int i = idx / 4, e = idx - i * 4;
    int col = (e < 2) ? e : 48 + e;
    xs[i][col] = 0.f;
  }
  __syncthreads();
  const int half = tid / 192;
  const int worker = tid - half * 192;
  const int og = worker / 12, wq = worker - og * 12;
  const int o0 = og * 7, w0 = wq * 4;
  const int ib = half * 56;  // this thread's contraction range [ib, ib+56)

  // ---- conv phase: acc = sum over own 56 input channels
  float acc[7][4];
#pragma unroll
  for (int j = 0; j < 7; ++j)
#pragma unroll
    for (int l = 0; l < 4; ++l) acc[j][l] = 0.f;
  for (int grp = 0; grp < 14; ++grp) {
    const int ii = ib + grp * 4;
    float4 u[8];
    load_u(u, xs, ii, w0);
#pragma unroll
    for (int j = 0; j < 7; ++j) {
      const float4* wp = (const float4*)&cw[((size_t)(o0 + j) * C_ + ii) * 3];
      float4 wv[3] = {wp[0], wp[1], wp[2]};
      conv_fma(acc[j], u, wv);
    }
  }
  // merge halves
  if (half == 1) {
#pragma unroll
    for (int j = 0; j < 7; ++j)
#pragma unroll
      for (int l = 0; l < 4; ++l) red[worker * 29 + j * 4 + l] = acc[j][l];
  }
  __syncthreads();
  float4 t13v[7];
  if (half == 0) {
#pragma unroll
    for (int j = 0; j < 7; ++j) {
#pragma unroll
      for (int l = 0; l < 4; ++l) acc[j][l] += red[worker * 29 + j * 4 + l];
      // t13 = max(-conv, x); x[w0+l] at col w0+l+2
      float4 xa = *(const float4*)&xs[o0 + j][w0];
      float4 xb2 = *(const float4*)&xs[o0 + j][w0 + 4];
      t13v[j].x = fmaxf(-acc[j][0], xa.z);
      t13v[j].y = fmaxf(-acc[j][1], xa.w);
      t13v[j].z = fmaxf(-acc[j][2], xb2.x);
      t13v[j].w = fmaxf(-acc[j][3], xb2.y);
    }
  }
  __syncthreads();  // conv x-reads complete before overwrite
  if (half == 0) {
#pragma unroll
    for (int j = 0; j < 7; ++j) *(float4*)&xs[o0 + j][w0] = t13v[j];
  }
  __syncthreads();  // t13 visible

  // ---- GEMM phase: acc2 = sum_i G[c,i]*t13[i], split over i halves
  const float* gp = ws + WS_G + (size_t)n * C_ * C_;
  float acc2[7][4];
#pragma unroll
  for (int j = 0; j < 7; ++j)
#pragma unroll
    for (int l = 0; l < 4; ++l) acc2[j][l] = 0.f;
  for (int grp = 0; grp < 14; ++grp) {
    const int ii = ib + grp * 4;
    float4 s[4];
#pragma unroll
    for (int r = 0; r < 4; ++r) s[r] = *(const float4*)&xs[ii + r][w0];
#pragma unroll
    for (int j = 0; j < 7; ++j) {
      float4 g = *(const float4*)&gp[(size_t)(o0 + j) * C_ + ii];
#pragma unroll
      for (int r = 0; r < 4; ++r) {
        float gv = f4e(g, r);
#pragma unroll
        for (int l = 0; l < 4; ++l) acc2[j][l] += gv * f4e(s[r], l);
      }
    }
  }
  if (half == 1) {
#pragma unroll
    for (int j = 0; j < 7; ++j)
#pragma unroll
      for (int l = 0; l < 4; ++l) red[worker * 29 + j * 4 + l] = acc2[j][l];
  }
  __syncthreads();
  if (half == 0) {
#pragma unroll
    for (int j = 0; j < 7; ++j) {
      float ap = ws[WS_A + n * C_ + o0 + j];
      float4 o;
      o.x = ap - (acc2[j][0] + red[worker * 29 + j * 4 + 0]);
      o.y = ap - (acc2[j][1] + red[worker * 29 + j * 4 + 1]);
      o.z = ap - (acc2[j][2] + red[worker * 29 + j * 4 + 2]);
      o.w = ap - (acc2[j][3] + red[worker * 29 + j * 4 + 3]);
      *(float4*)&out[((size_t)n * C_ + o0 + j) * HW_ + h * W_ + w0] = o;
    }
  }
}

// ---------------------------------------------------------------------------
extern "C" void kernel_launch(void* const* d_in, const int* in_sizes, int n_in,
                              void* d_out, int out_size, void* d_ws, size_t ws_size,
                              hipStream_t stream) {
  const float* x = (const float*)d_in[0];
  const float* p7 = (const float*)d_in[1];
  // d_in[2] (p8_w) cancels algebraically: t10 = t8 - (x + t8) = -x
  const float* p19 = (const float*)d_in[3];
  const float* cw = (const float*)d_in[4];
  float* ws = (float*)d_ws;
  float* out = (float*)d_out;

  const int ladder[10] = {48, 24, 16, 12, 8, 6, 4, 3, 2, 1};
  int nch = 1;
  for (int li = 0; li < 10; ++li) {
    size_t need = ((size_t)WS_SPART + (size_t)ladder[li] * N_ * C_ * C_) * sizeof(float);
    if (need <= ws_size) { nch = ladder[li]; break; }
  }
  const int KC = HW_ / nch;

  ath_stats<<<dim3(16, N_), 192, 0, stream>>>(x, p7, ws);
  ath_colstats<<<dim3(C_, N_), 64, 0, stream>>>(x, p19, ws);
  ath_gram<<<N_ * nch, 256, 0, stream>>>(x, ws, nch, KC);
  ath_assemble<<<(N_ * C_ * C_ / 4 + 255) / 256, 256, 0, stream>>>(p19, ws, nch);
  ath_fused<<<dim3(H_, N_), 384, 0, stream>>>(x, cw, ws, out);
}

// Round 7
// 97.722 us; speedup vs baseline: 1.6143x; 1.6143x over previous
//
#include <hip/hip_runtime.h>

typedef __attribute__((ext_vector_type(8))) short bfrag;   // 8 bf16 = 4 VGPR
typedef __attribute__((ext_vector_type(4))) float f32x4;

namespace {
constexpr int N_ = 16, C_ = 112, H_ = 48, W_ = 48, HW_ = 2304;
// ws float offsets
constexpr int WS_T7 = 0;          // 768
constexpr int WS_T17 = 768;       // 112
constexpr int WS_A = 1024;        // 1792
constexpr int WS_V = 4096;        // 12544
constexpr int WS_WPACK = 16896;   // 3*112*128 bf16 = 21504 floats
constexpr int WS_GBF = 38400;     // 16*112*128 bf16 = 114688 floats
constexpr int WS_SPART = 153088;  // nch*16*12544 floats
}

__device__ __forceinline__ float f4e(const float4& v, int e) {
  return e == 0 ? v.x : e == 1 ? v.y : e == 2 ? v.z : v.w;
}
__device__ __forceinline__ unsigned short f2bf(float f) {  // RNE
  unsigned u = __float_as_uint(f);
  return (unsigned short)((u + 0x7FFFu + ((u >> 16) & 1u)) >> 16);
}
__device__ __forceinline__ float bf2f(unsigned short s) {
  return __uint_as_float(((unsigned)s) << 16);
}

// ---------------------------------------------------------------------------
// K1: channel-mean rows -> t7; value from mean-row h' lands at (h'+2)%48.
__global__ __launch_bounds__(192) void ath_stats(const float* __restrict__ x,
                                                 const float* __restrict__ p7,
                                                 float* __restrict__ ws) {
  const int hg = blockIdx.x;
  const int n = blockIdx.y;
  const int tid = threadIdx.x;
  __shared__ float mxs[144];
  if (tid < 144) {
    const float* xb = x + (size_t)n * C_ * HW_ + hg * 144 + tid;
    float a0 = 0.f, a1 = 0.f, a2 = 0.f, a3 = 0.f;
    for (int c = 0; c < C_; c += 4) {
      a0 += xb[(size_t)c * HW_];
      a1 += xb[(size_t)(c + 1) * HW_];
      a2 += xb[(size_t)(c + 2) * HW_];
      a3 += xb[(size_t)(c + 3) * HW_];
    }
    mxs[tid] = (a0 + a1 + a2 + a3) * (1.0f / 112.0f);
  }
  __syncthreads();
  if (tid < 3) {
    float s = 0.f;
    for (int k = 0; k < 3; ++k)
      for (int wp = 0; wp < W_; ++wp) {
        int j = 3 * k + wp - 3;
        if (j >= 0 && j < W_) s += mxs[tid * 48 + j] * p7[k * W_ + wp];
      }
    const int hsrc = hg * 3 + tid;
    ws[WS_T7 + n * H_ + (hsrc + 2) % 48] = s;
  }
}

// ---------------------------------------------------------------------------
// K1b: pack conv weights as bf16 [kx][o][i(pad 128)]
__global__ __launch_bounds__(256) void ath_wpack(const float* __restrict__ cw,
                                                 float* __restrict__ ws) {
  int idx = blockIdx.x * 256 + threadIdx.x;  // over 3*112*32 quads
  if (idx >= 3 * 112 * 32) return;
  int kx = idx / (112 * 32);
  int r = idx - kx * 112 * 32;
  int o = r >> 5;
  int i0 = (r & 31) * 4;
  unsigned short v[4];
#pragma unroll
  for (int e = 0; e < 4; ++e) {
    int i = i0 + e;
    v[e] = (i < 112) ? f2bf(cw[o * 336 + i * 3 + kx]) : (unsigned short)0;
  }
  unsigned short* wp = (unsigned short*)(ws + WS_WPACK);
  *(ushort4*)&wp[(kx * 112 + o) * 128 + i0] = make_ushort4(v[0], v[1], v[2], v[3]);
}

// ---------------------------------------------------------------------------
// K3: per (n,c): V buckets + A'; t17 computed locally, c==0 publishes.
__global__ __launch_bounds__(64) void ath_colstats(const float* __restrict__ x,
                                                   const float* __restrict__ p19,
                                                   float* __restrict__ ws) {
  const int c = blockIdx.x, n = blockIdx.y;
  const int tid = threadIdx.x;
  __shared__ float t7s[48];
  if (tid < 48) t7s[tid] = ws[WS_T7 + n * H_ + tid];
  const float* xb = x + ((size_t)n * C_ + c) * HW_;
  float rowsum = 0.f;
  if (tid < 48) {
    const float4* xr = (const float4*)(xb + tid * W_);
#pragma unroll
    for (int q = 0; q < 12; ++q) {
      float4 v = xr[q];
      rowsum += v.x + v.y + v.z + v.w;
    }
  }
  float vb[7] = {0.f, 0.f, 0.f, 0.f, 0.f, 0.f, 0.f};
#pragma unroll
  for (int jj = 0; jj < 9; ++jj) {
    int p0 = (tid + 64 * jj) * 4;
    float4 v = *(const float4*)&xb[p0];
    int h = p0 / 48;
    int w = p0 - h * 48;
    int m0 = (w - h + 49) % 7;
#pragma unroll
    for (int r = 0; r < 4; ++r) {
      int mr = m0 + r;
      mr = (mr >= 7) ? mr - 7 : mr;
      float val = f4e(v, r);
#pragma unroll
      for (int j = 0; j < 7; ++j) vb[j] += (mr == j) ? val : 0.f;
    }
  }
#pragma unroll
  for (int j = 0; j < 7; ++j) {
#pragma unroll
    for (int off = 32; off >= 1; off >>= 1) vb[j] += __shfl_xor(vb[j], off);
  }
  if (tid == 0) {
#pragma unroll
    for (int j = 0; j < 7; ++j) ws[WS_V + ((size_t)n * C_ + c) * 7 + j] = vb[j];
  }
  float t17l[7];
  float T = 0.f;
#pragma unroll
  for (int kk = 0; kk < 7; ++kk) {
    float s = 0.f;
    for (int hh = 0; hh < 48; ++hh) {
      int j = 2 * kk + hh - 6;
      if (j >= 0 && j < 48) s += fabsf(t7s[j]);
    }
    t17l[kk] = s * (1.0f / 48.0f);
    T += t17l[kk];
  }
  if (c == 0 && tid < 7) ws[WS_T17 + n * 7 + tid] = t17l[tid];
  float term = 0.f;
  if (tid < 48) {
    int idx6 = ((c - tid + 6) % 7 + 7) % 7;
    float D = 7.f * T - t17l[idx6];
    term = t7s[tid] * (rowsum + D);
  }
#pragma unroll
  for (int off = 32; off >= 1; off >>= 1) term += __shfl_xor(term, off);
  if (tid == 0) ws[WS_A + n * C_ + c] = p19[c] * term * (2.0f / 48.0f);
}

// ---------------------------------------------------------------------------
// K4: Gram partials (f32, unchanged structure)
__global__ __launch_bounds__(256) void ath_gram(const float* __restrict__ x,
                                                float* __restrict__ ws,
                                                int nch, int KC) {
  const int bid = blockIdx.x;
  const int n = bid / nch;
  const int kc = bid - n * nch;
  const int p0 = kc * KC;
  const int tid = threadIdx.x;
  __shared__ float xs[48][132];
  for (int idx = tid; idx < 48 * 16; idx += 256) {
    int k = idx / 16, cc = 112 + (idx % 16);
    xs[k][cc] = 0.f;
  }
  float acc[8][8];
#pragma unroll
  for (int a = 0; a < 8; ++a)
#pragma unroll
    for (int b = 0; b < 8; ++b) acc[a][b] = 0.f;
  const int tc = tid >> 4, ti = tid & 15;
  const int c0 = tc * 8, i0 = ti * 8;
  const float* xb = x + (size_t)n * C_ * HW_;
  for (int ks = 0; ks < KC; ks += 48) {
    __syncthreads();
    for (int idx = tid; idx < C_ * 48; idx += 256) {
      int cc = idx / 48, k = idx - cc * 48;
      xs[k][cc] = xb[(size_t)cc * HW_ + p0 + ks + k];
    }
    __syncthreads();
#pragma unroll 2
    for (int k = 0; k < 48; ++k) {
      float4 a0 = *(const float4*)&xs[k][c0];
      float4 a1 = *(const float4*)&xs[k][c0 + 4];
      float4 b0 = *(const float4*)&xs[k][i0];
      float4 b1 = *(const float4*)&xs[k][i0 + 4];
      float av[8] = {a0.x, a0.y, a0.z, a0.w, a1.x, a1.y, a1.z, a1.w};
      float bv[8] = {b0.x, b0.y, b0.z, b0.w, b1.x, b1.y, b1.z, b1.w};
#pragma unroll
      for (int r = 0; r < 8; ++r)
#pragma unroll
        for (int q = 0; q < 8; ++q) acc[r][q] += av[r] * bv[q];
    }
  }
  if (c0 < 112 && i0 < 112) {
    float* sp = ws + WS_SPART + (size_t)bid * (C_ * C_);
#pragma unroll
    for (int r = 0; r < 8; ++r) {
      *(float4*)&sp[(c0 + r) * C_ + i0] =
          make_float4(acc[r][0], acc[r][1], acc[r][2], acc[r][3]);
      *(float4*)&sp[(c0 + r) * C_ + i0 + 4] =
          make_float4(acc[r][4], acc[r][5], acc[r][6], acc[r][7]);
    }
  }
}

// ---------------------------------------------------------------------------
// K5: assemble G' -> bf16 Gbf[n][c][i pad 128]
__global__ __launch_bounds__(256) void ath_assemble(const float* __restrict__ p19,
                                                    float* __restrict__ ws,
                                                    int nch) {
  int idx = blockIdx.x * 256 + threadIdx.x;  // over N*C*32 quads
  if (idx >= N_ * C_ * 32) return;
  int n = idx / (C_ * 32);
  int r = idx - n * C_ * 32;
  int c = r >> 5;
  int i0 = (r & 31) * 4;
  unsigned short v[4] = {0, 0, 0, 0};
  if (i0 < 112) {
    float4 s = make_float4(0.f, 0.f, 0.f, 0.f);
    for (int kc = 0; kc < nch; ++kc) {
      float4 t = *(const float4*)&ws[WS_SPART + (size_t)(n * nch + kc) * 12544 + c * C_ + i0];
      s.x += t.x; s.y += t.y; s.z += t.z; s.w += t.w;
    }
    const float* t17p = ws + WS_T17 + n * 7;
    const float scale = 1.0f / (48.0f * sqrtf(112.0f));
    const float pc = p19[c];
    int j0 = c % 7;
#pragma unroll
    for (int e = 0; e < 4; ++e) {
      const float* vp = ws + WS_V + ((size_t)n * C_ + i0 + e) * 7;
      float t = 0.f;
#pragma unroll
      for (int m = 0; m < 7; ++m) {
        int jj = j0 + m;
        jj = (jj >= 7) ? jj - 7 : jj;
        t += t17p[jj] * vp[m];
      }
      v[e] = f2bf(pc * (f4e(s, e) + t) * scale);
    }
  }
  unsigned short* gb = (unsigned short*)(ws + WS_GBF);
  *(ushort4*)&gb[((size_t)n * C_ + c) * 128 + i0] = make_ushort4(v[0], v[1], v[2], v[3]);
}

// ---------------------------------------------------------------------------
// K6 fused via MFMA. xT[52][136] bf16: row r = w+2 (rows 0,1,50,51 zero);
// cols 112..135 zero (K-pad). conv = 3 shift-GEMMs vs wpack; t13 in-place;
// final GEMM vs Gbf. 21 16x16 tiles round-robin over 4 waves.
__global__ __launch_bounds__(256) void ath_fused(const float* __restrict__ x,
                                                 const float* __restrict__ ws,
                                                 float* __restrict__ out) {
  const int h = blockIdx.x, n = blockIdx.y;
  const int tid = threadIdx.x;
  const int lane = tid & 63, wv = tid >> 6;
  const int lr = lane & 15, lg = lane >> 4;
  __shared__ __align__(16) unsigned short xT[52][136];
  __shared__ float sA[112];
  const float* xb = x + (size_t)n * C_ * HW_ + h * W_;
  // zero pads
  for (int idx = tid; idx < 52 * 24; idx += 256) {
    int r2 = idx / 24, cc = 112 + idx % 24;
    xT[r2][cc] = 0;
  }
  for (int idx = tid; idx < 4 * 112; idx += 256) {
    int rr = idx / 112;
    int r2 = (rr < 2) ? rr : 48 + rr;
    xT[r2][idx % 112] = 0;
  }
  if (tid < 112) sA[tid] = ws[WS_A + n * C_ + tid];
  // stage x -> xT bf16 (transpose)
  for (int idx = tid; idx < C_ * 12; idx += 256) {
    int i = idx / 12, q = idx - i * 12;
    float4 v = *(const float4*)&xb[(size_t)i * HW_ + 4 * q];
    xT[4 * q + 2][i] = f2bf(v.x);
    xT[4 * q + 3][i] = f2bf(v.y);
    xT[4 * q + 4][i] = f2bf(v.z);
    xT[4 * q + 5][i] = f2bf(v.w);
  }
  __syncthreads();
  const unsigned short* wp = (const unsigned short*)(ws + WS_WPACK);
  const unsigned short* gb = (const unsigned short*)(ws + WS_GBF) + (size_t)n * C_ * 128;

  // ---- conv phase: D[o][w] = sum_{kx,i} W[kx][o][i] * x[i][w+2kx-2]
  unsigned short tv[6][4];
#pragma unroll
  for (int j = 0; j < 6; ++j) {
    int t = wv + 4 * j;
    if (t < 21) {
      int m = t / 3, nt = t - 3 * m;
      int o0 = m * 16, w0 = nt * 16;
      f32x4 acc = {0.f, 0.f, 0.f, 0.f};
#pragma unroll
      for (int kx = 0; kx < 3; ++kx) {
        const unsigned short* arow = wp + ((kx * 112 + o0 + lr) * 128 + 8 * lg);
        const unsigned short* brow = &xT[w0 + lr + 2 * kx][8 * lg];
#pragma unroll
        for (int ks = 0; ks < 4; ++ks) {
          bfrag a = *(const bfrag*)(arow + 32 * ks);
          bfrag b = *(const bfrag*)(brow + 32 * ks);
          acc = __builtin_amdgcn_mfma_f32_16x16x32_bf16(a, b, acc, 0, 0, 0);
        }
      }
#pragma unroll
      for (int e = 0; e < 4; ++e) {
        float xv = bf2f(xT[w0 + lr + 2][o0 + 4 * lg + e]);
        tv[j][e] = f2bf(fmaxf(-acc[e], xv));  // t13 = max(-conv, x)
      }
    }
  }
  __syncthreads();  // all conv reads of xT complete
#pragma unroll
  for (int j = 0; j < 6; ++j) {
    int t = wv + 4 * j;
    if (t < 21) {
      int m = t / 3, nt = t - 3 * m;
      int o0 = m * 16, w0 = nt * 16;
      unsigned pk0 = (unsigned)tv[j][0] | ((unsigned)tv[j][1] << 16);
      unsigned pk1 = (unsigned)tv[j][2] | ((unsigned)tv[j][3] << 16);
      *(unsigned*)&xT[w0 + lr + 2][o0 + 4 * lg] = pk0;
      *(unsigned*)&xT[w0 + lr + 2][o0 + 4 * lg + 2] = pk1;
    }
  }
  __syncthreads();  // t13T visible

  // ---- final GEMM: out[c][w] = A'[c] - sum_i G'[c][i] * t13[i][w]
#pragma unroll
  for (int j = 0; j < 6; ++j) {
    int t = wv + 4 * j;
    if (t < 21) {
      int m = t / 3, nt = t - 3 * m;
      int c0 = m * 16, w0 = nt * 16;
      f32x4 acc = {0.f, 0.f, 0.f, 0.f};
      const unsigned short* arow = gb + ((c0 + lr) * 128 + 8 * lg);
      const unsigned short* brow = &xT[w0 + lr + 2][8 * lg];
#pragma unroll
      for (int ks = 0; ks < 4; ++ks) {
        bfrag a = *(const bfrag*)(arow + 32 * ks);
        bfrag b = *(const bfrag*)(brow + 32 * ks);
        acc = __builtin_amdgcn_mfma_f32_16x16x32_bf16(a, b, acc, 0, 0, 0);
      }
#pragma unroll
      for (int e = 0; e < 4; ++e) {
        int c = c0 + 4 * lg + e;
        out[((size_t)n * C_ + c) * HW_ + h * W_ + w0 + lr] = sA[c] - acc[e];
      }
    }
  }
}

// ---------------------------------------------------------------------------
extern "C" void kernel_launch(void* const* d_in, const int* in_sizes, int n_in,
                              void* d_out, int out_size, void* d_ws, size_t ws_size,
                              hipStream_t stream) {
  const float* x = (const float*)d_in[0];
  const float* p7 = (const float*)d_in[1];
  // d_in[2] (p8_w) cancels algebraically: t10 = t8 - (x + t8) = -x
  const float* p19 = (const float*)d_in[3];
  const float* cw = (const float*)d_in[4];
  float* ws = (float*)d_ws;
  float* out = (float*)d_out;

  const int ladder[10] = {48, 24, 16, 12, 8, 6, 4, 3, 2, 1};
  int nch = 1;
  for (int li = 0; li < 10; ++li) {
    size_t need = ((size_t)WS_SPART + (size_t)ladder[li] * N_ * C_ * C_) * sizeof(float);
    if (need <= ws_size) { nch = ladder[li]; break; }
  }
  const int KC = HW_ / nch;

  ath_stats<<<dim3(16, N_), 192, 0, stream>>>(x, p7, ws);
  ath_wpack<<<42, 256, 0, stream>>>(cw, ws);
  ath_colstats<<<dim3(C_, N_), 64, 0, stream>>>(x, p19, ws);
  ath_gram<<<N_ * nch, 256, 0, stream>>>(x, ws, nch, KC);
  ath_assemble<<<224, 256, 0, stream>>>(p19, ws, nch);
  ath_fused<<<dim3(H_, N_), 256, 0, stream>>>(x, ws, out);
}

// Round 8
// 73.484 us; speedup vs baseline: 2.1468x; 1.3298x over previous
//
#include <hip/hip_runtime.h>

typedef __attribute__((ext_vector_type(8))) short bfrag;   // 8 bf16 = 4 VGPR
typedef __attribute__((ext_vector_type(4))) float f32x4;

namespace {
constexpr int N_ = 16, C_ = 112, H_ = 48, W_ = 48, HW_ = 2304;
constexpr int NKS = 18;  // K-slices of 128 for gram (18*128 = 2304)
// ws float offsets
constexpr int WS_T7 = 0;          // 768
constexpr int WS_T17 = 768;       // 112
constexpr int WS_A = 1024;        // 1792
constexpr int WS_V = 4096;        // 12544 -> ends 16640
constexpr int WS_MX = 16640;      // N*HW channel-sums = 36864 -> ends 53504
constexpr int WS_WPACK = 53504;   // 3*112*128 bf16 = 21504 floats -> ends 75008
constexpr int WS_GBF = 75008;     // 16*112*128 bf16 = 114688 floats -> ends 189696
constexpr int WS_SPART = 189696;  // 18*16*12544 f32 = 3612672 -> ends ~3.8M floats
}

__device__ __forceinline__ float f4e(const float4& v, int e) {
  return e == 0 ? v.x : e == 1 ? v.y : e == 2 ? v.z : v.w;
}
__device__ __forceinline__ unsigned short f2bf(float f) {  // RNE
  unsigned u = __float_as_uint(f);
  return (unsigned short)((u + 0x7FFFu + ((u >> 16) & 1u)) >> 16);
}
__device__ __forceinline__ float bf2f(unsigned short s) {
  return __uint_as_float(((unsigned)s) << 16);
}

// ---------------------------------------------------------------------------
// K1b: pack conv weights as bf16 [kx][o][i(pad 128)]
__global__ __launch_bounds__(256) void ath_wpack(const float* __restrict__ cw,
                                                 float* __restrict__ ws) {
  int idx = blockIdx.x * 256 + threadIdx.x;  // over 3*112*32 quads
  if (idx >= 3 * 112 * 32) return;
  int kx = idx / (112 * 32);
  int r = idx - kx * 112 * 32;
  int o = r >> 5;
  int i0 = (r & 31) * 4;
  unsigned short v[4];
#pragma unroll
  for (int e = 0; e < 4; ++e) {
    int i = i0 + e;
    v[e] = (i < 112) ? f2bf(cw[o * 336 + i * 3 + kx]) : (unsigned short)0;
  }
  unsigned short* wp = (unsigned short*)(ws + WS_WPACK);
  *(ushort4*)&wp[(kx * 112 + o) * 128 + i0] = make_ushort4(v[0], v[1], v[2], v[3]);
}

// ---------------------------------------------------------------------------
// K2: Gram via MFMA + fused channel-sum. grid (NKS, N), 256 threads.
// Per block: stage x[n, :, k0:k0+128] as bf16 LDS slab, column-sum over c
// -> ws_mx[n][k-slice]; 49 16x16 S-tiles (S[c,i] = sum_k X[c,k]X[i,k])
// -> SPART[n*NKS+ks].
__global__ __launch_bounds__(256) void ath_gram(const float* __restrict__ x,
                                                float* __restrict__ ws) {
  const int ks = blockIdx.x, n = blockIdx.y;
  const int k0 = ks * 128;
  const int tid = threadIdx.x;
  const int lane = tid & 63, wv = tid >> 6;
  const int lr = lane & 15, lg = lane >> 4;
  __shared__ __align__(16) unsigned short xbs[112][136];  // 272B row stride
  __shared__ float4 csred[256];
  // load + convert + per-thread column partial sums
  const int kq = tid & 31;  // col-quad (16B) 0..31
  const int cg = tid >> 5;  // 0..7
  float4 cs = make_float4(0.f, 0.f, 0.f, 0.f);
#pragma unroll
  for (int r = 0; r < 14; ++r) {
    const int c = cg + 8 * r;
    float4 v = *(const float4*)&x[((size_t)n * C_ + c) * HW_ + k0 + 4 * kq];
    cs.x += v.x; cs.y += v.y; cs.z += v.z; cs.w += v.w;
    *(ushort4*)&xbs[c][4 * kq] =
        make_ushort4(f2bf(v.x), f2bf(v.y), f2bf(v.z), f2bf(v.w));
  }
  csred[tid] = cs;
  __syncthreads();
  if (tid < 32) {
    float4 s = csred[tid];
#pragma unroll
    for (int g = 1; g < 8; ++g) {
      float4 t = csred[tid + 32 * g];
      s.x += t.x; s.y += t.y; s.z += t.z; s.w += t.w;
    }
    *(float4*)&ws[WS_MX + n * HW_ + k0 + 4 * tid] = s;
  }
  // MFMA: 49 tiles round-robin over 4 waves
  f32x4 acc[13];
#pragma unroll
  for (int j = 0; j < 13; ++j) acc[j] = (f32x4){0.f, 0.f, 0.f, 0.f};
#pragma unroll
  for (int j = 0; j < 13; ++j) {
    int t = wv + 4 * j;
    if (t < 49) {
      int tc = t / 7, ti = t - 7 * tc;
      const unsigned short* arow = &xbs[16 * tc + lr][8 * lg];
      const unsigned short* brow = &xbs[16 * ti + lr][8 * lg];
#pragma unroll
      for (int kb = 0; kb < 4; ++kb) {
        bfrag a = *(const bfrag*)(arow + 32 * kb);
        bfrag b = *(const bfrag*)(brow + 32 * kb);
        acc[j] = __builtin_amdgcn_mfma_f32_16x16x32_bf16(a, b, acc[j], 0, 0, 0);
      }
    }
  }
  float* sp = ws + WS_SPART + (size_t)(n * NKS + ks) * 12544;
#pragma unroll
  for (int j = 0; j < 13; ++j) {
    int t = wv + 4 * j;
    if (t < 49) {
      int tc = t / 7, ti = t - 7 * tc;
#pragma unroll
      for (int e = 0; e < 4; ++e)
        sp[(16 * tc + 4 * lg + e) * C_ + 16 * ti + lr] = acc[j][e];
    }
  }
}

// ---------------------------------------------------------------------------
// K2b: t7 from channel-sums. grid N, 64 threads.
// t7 value computed from mean-row h' lands at (h'+2)%48 (S3=+1,S6=+1 rolls).
__global__ __launch_bounds__(64) void ath_t7(const float* __restrict__ p7,
                                             float* __restrict__ ws) {
  const int n = blockIdx.x;
  const int tid = threadIdx.x;
  __shared__ float mxs[2304];
  for (int idx = tid; idx < HW_; idx += 64)
    mxs[idx] = ws[WS_MX + n * HW_ + idx] * (1.0f / 112.0f);
  __syncthreads();
  if (tid < 48) {
    float s = 0.f;
    for (int k = 0; k < 3; ++k)
      for (int wp = 0; wp < W_; ++wp) {
        int j = 3 * k + wp - 3;
        if (j >= 0 && j < W_) s += mxs[tid * 48 + j] * p7[k * W_ + wp];
      }
    ws[WS_T7 + n * H_ + (tid + 2) % 48] = s;
  }
}

// ---------------------------------------------------------------------------
// K3: per (n,c): V buckets + A'; t17 computed locally, c==0 publishes.
__global__ __launch_bounds__(64) void ath_colstats(const float* __restrict__ x,
                                                   const float* __restrict__ p19,
                                                   float* __restrict__ ws) {
  const int c = blockIdx.x, n = blockIdx.y;
  const int tid = threadIdx.x;
  __shared__ float t7s[48];
  if (tid < 48) t7s[tid] = ws[WS_T7 + n * H_ + tid];
  const float* xb = x + ((size_t)n * C_ + c) * HW_;
  float rowsum = 0.f;
  if (tid < 48) {
    const float4* xr = (const float4*)(xb + tid * W_);
#pragma unroll
    for (int q = 0; q < 12; ++q) {
      float4 v = xr[q];
      rowsum += v.x + v.y + v.z + v.w;
    }
  }
  float vb[7] = {0.f, 0.f, 0.f, 0.f, 0.f, 0.f, 0.f};
#pragma unroll
  for (int jj = 0; jj < 9; ++jj) {
    int p0 = (tid + 64 * jj) * 4;
    float4 v = *(const float4*)&xb[p0];
    int h = p0 / 48;
    int w = p0 - h * 48;
    int m0 = (w - h + 49) % 7;
#pragma unroll
    for (int r = 0; r < 4; ++r) {
      int mr = m0 + r;
      mr = (mr >= 7) ? mr - 7 : mr;
      float val = f4e(v, r);
#pragma unroll
      for (int j = 0; j < 7; ++j) vb[j] += (mr == j) ? val : 0.f;
    }
  }
#pragma unroll
  for (int j = 0; j < 7; ++j) {
#pragma unroll
    for (int off = 32; off >= 1; off >>= 1) vb[j] += __shfl_xor(vb[j], off);
  }
  if (tid == 0) {
#pragma unroll
    for (int j = 0; j < 7; ++j) ws[WS_V + ((size_t)n * C_ + c) * 7 + j] = vb[j];
  }
  float t17l[7];
  float T = 0.f;
#pragma unroll
  for (int kk = 0; kk < 7; ++kk) {
    float s = 0.f;
    for (int hh = 0; hh < 48; ++hh) {
      int j = 2 * kk + hh - 6;
      if (j >= 0 && j < 48) s += fabsf(t7s[j]);
    }
    t17l[kk] = s * (1.0f / 48.0f);
    T += t17l[kk];
  }
  if (c == 0 && tid < 7) ws[WS_T17 + n * 7 + tid] = t17l[tid];
  float term = 0.f;
  if (tid < 48) {
    int idx6 = ((c - tid + 6) % 7 + 7) % 7;
    float D = 7.f * T - t17l[idx6];
    term = t7s[tid] * (rowsum + D);
  }
#pragma unroll
  for (int off = 32; off >= 1; off >>= 1) term += __shfl_xor(term, off);
  if (tid == 0) ws[WS_A + n * C_ + c] = p19[c] * term * (2.0f / 48.0f);
}

// ---------------------------------------------------------------------------
// K5: assemble G' -> bf16 Gbf[n][c][i pad 128]
__global__ __launch_bounds__(256) void ath_assemble(const float* __restrict__ p19,
                                                    float* __restrict__ ws) {
  int idx = blockIdx.x * 256 + threadIdx.x;  // over N*C*32 quads
  if (idx >= N_ * C_ * 32) return;
  int n = idx / (C_ * 32);
  int r = idx - n * C_ * 32;
  int c = r >> 5;
  int i0 = (r & 31) * 4;
  unsigned short v[4] = {0, 0, 0, 0};
  if (i0 < 112) {
    float4 s = make_float4(0.f, 0.f, 0.f, 0.f);
    for (int kc = 0; kc < NKS; ++kc) {
      float4 t = *(const float4*)&ws[WS_SPART + (size_t)(n * NKS + kc) * 12544 + c * C_ + i0];
      s.x += t.x; s.y += t.y; s.z += t.z; s.w += t.w;
    }
    const float* t17p = ws + WS_T17 + n * 7;
    const float scale = 1.0f / (48.0f * sqrtf(112.0f));
    const float pc = p19[c];
    int j0 = c % 7;
#pragma unroll
    for (int e = 0; e < 4; ++e) {
      const float* vp = ws + WS_V + ((size_t)n * C_ + i0 + e) * 7;
      float t = 0.f;
#pragma unroll
      for (int m = 0; m < 7; ++m) {
        int jj = j0 + m;
        jj = (jj >= 7) ? jj - 7 : jj;
        t += t17p[jj] * vp[m];
      }
      v[e] = f2bf(pc * (f4e(s, e) + t) * scale);
    }
  }
  unsigned short* gb = (unsigned short*)(ws + WS_GBF);
  *(ushort4*)&gb[((size_t)n * C_ + c) * 128 + i0] = make_ushort4(v[0], v[1], v[2], v[3]);
}

// ---------------------------------------------------------------------------
// K6 fused via MFMA. xT[52][136] bf16: row r = w+2 (rows 0,1,50,51 zero);
// cols 112..135 zero (K-pad). conv = 3 shift-GEMMs vs wpack; t13 in-place;
// final GEMM vs Gbf. 21 16x16 tiles round-robin over 4 waves.
__global__ __launch_bounds__(256) void ath_fused(const float* __restrict__ x,
                                                 const float* __restrict__ ws,
                                                 float* __restrict__ out) {
  const int h = blockIdx.x, n = blockIdx.y;
  const int tid = threadIdx.x;
  const int lane = tid & 63, wv = tid >> 6;
  const int lr = lane & 15, lg = lane >> 4;
  __shared__ __align__(16) unsigned short xT[52][136];
  __shared__ float sA[112];
  const float* xb = x + (size_t)n * C_ * HW_ + h * W_;
  for (int idx = tid; idx < 52 * 24; idx += 256) {
    int r2 = idx / 24, cc = 112 + idx % 24;
    xT[r2][cc] = 0;
  }
  for (int idx = tid; idx < 4 * 112; idx += 256) {
    int rr = idx / 112;
    int r2 = (rr < 2) ? rr : 48 + rr;
    xT[r2][idx % 112] = 0;
  }
  if (tid < 112) sA[tid] = ws[WS_A + n * C_ + tid];
  for (int idx = tid; idx < C_ * 12; idx += 256) {
    int i = idx / 12, q = idx - i * 12;
    float4 v = *(const float4*)&xb[(size_t)i * HW_ + 4 * q];
    xT[4 * q + 2][i] = f2bf(v.x);
    xT[4 * q + 3][i] = f2bf(v.y);
    xT[4 * q + 4][i] = f2bf(v.z);
    xT[4 * q + 5][i] = f2bf(v.w);
  }
  __syncthreads();
  const unsigned short* wp = (const unsigned short*)(ws + WS_WPACK);
  const unsigned short* gb = (const unsigned short*)(ws + WS_GBF) + (size_t)n * C_ * 128;

  unsigned short tv[6][4];
#pragma unroll
  for (int j = 0; j < 6; ++j) {
    int t = wv + 4 * j;
    if (t < 21) {
      int m = t / 3, nt = t - 3 * m;
      int o0 = m * 16, w0 = nt * 16;
      f32x4 acc = {0.f, 0.f, 0.f, 0.f};
#pragma unroll
      for (int kx = 0; kx < 3; ++kx) {
        const unsigned short* arow = wp + ((kx * 112 + o0 + lr) * 128 + 8 * lg);
        const unsigned short* brow = &xT[w0 + lr + 2 * kx][8 * lg];
#pragma unroll
        for (int ks = 0; ks < 4; ++ks) {
          bfrag a = *(const bfrag*)(arow + 32 * ks);
          bfrag b = *(const bfrag*)(brow + 32 * ks);
          acc = __builtin_amdgcn_mfma_f32_16x16x32_bf16(a, b, acc, 0, 0, 0);
        }
      }
#pragma unroll
      for (int e = 0; e < 4; ++e) {
        float xv = bf2f(xT[w0 + lr + 2][o0 + 4 * lg + e]);
        tv[j][e] = f2bf(fmaxf(-acc[e], xv));  // t13 = max(-conv, x)
      }
    }
  }
  __syncthreads();
#pragma unroll
  for (int j = 0; j < 6; ++j) {
    int t = wv + 4 * j;
    if (t < 21) {
      int m = t / 3, nt = t - 3 * m;
      int o0 = m * 16, w0 = nt * 16;
      unsigned pk0 = (unsigned)tv[j][0] | ((unsigned)tv[j][1] << 16);
      unsigned pk1 = (unsigned)tv[j][2] | ((unsigned)tv[j][3] << 16);
      *(unsigned*)&xT[w0 + lr + 2][o0 + 4 * lg] = pk0;
      *(unsigned*)&xT[w0 + lr + 2][o0 + 4 * lg + 2] = pk1;
    }
  }
  __syncthreads();
#pragma unroll
  for (int j = 0; j < 6; ++j) {
    int t = wv + 4 * j;
    if (t < 21) {
      int m = t / 3, nt = t - 3 * m;
      int c0 = m * 16, w0 = nt * 16;
      f32x4 acc = {0.f, 0.f, 0.f, 0.f};
      const unsigned short* arow = gb + ((c0 + lr) * 128 + 8 * lg);
      const unsigned short* brow = &xT[w0 + lr + 2][8 * lg];
#pragma unroll
      for (int ks = 0; ks < 4; ++ks) {
        bfrag a = *(const bfrag*)(arow + 32 * ks);
        bfrag b = *(const bfrag*)(brow + 32 * ks);
        acc = __builtin_amdgcn_mfma_f32_16x16x32_bf16(a, b, acc, 0, 0, 0);
      }
#pragma unroll
      for (int e = 0; e < 4; ++e) {
        int c = c0 + 4 * lg + e;
        out[((size_t)n * C_ + c) * HW_ + h * W_ + w0 + lr] = sA[c] - acc[e];
      }
    }
  }
}

// ---------------------------------------------------------------------------
extern "C" void kernel_launch(void* const* d_in, const int* in_sizes, int n_in,
                              void* d_out, int out_size, void* d_ws, size_t ws_size,
                              hipStream_t stream) {
  const float* x = (const float*)d_in[0];
  const float* p7 = (const float*)d_in[1];
  // d_in[2] (p8_w) cancels algebraically: t10 = t8 - (x + t8) = -x
  const float* p19 = (const float*)d_in[3];
  const float* cw = (const float*)d_in[4];
  float* ws = (float*)d_ws;
  float* out = (float*)d_out;

  ath_wpack<<<42, 256, 0, stream>>>(cw, ws);
  ath_gram<<<dim3(NKS, N_), 256, 0, stream>>>(x, ws);
  ath_t7<<<N_, 64, 0, stream>>>(p7, ws);
  ath_colstats<<<dim3(C_, N_), 64, 0, stream>>>(x, p19, ws);
  ath_assemble<<<224, 256, 0, stream>>>(p19, ws);
  ath_fused<<<dim3(H_, N_), 256, 0, stream>>>(x, ws, out);
}